// Round 1
// baseline (22.680 us; speedup 1.0000x reference)
//
#include <hip/hip_runtime.h>

// One-sided Chamfer: out[b][m] = min_n || point[b][m] - input[b][n] ||^2
// B=2, N=8192, M=8192, D=3, fp32.
//
// Strategy: compute-bound brute force.
//   t = 0.5*|q|^2 - p.q   (3 FMA per pair, q2h precomputed in LDS float4.w)
//   d2 = max(2*t_min + |p|^2, 0)
// Grid split over N (NSPLIT slices); partial slice minima merged via
// atomicMin on the uint bit pattern (exact & deterministic for d2 >= 0).

constexpr int BB = 2;
constexpr int NN = 8192;
constexpr int MM = 8192;

constexpr int BQ = 256;           // threads per block
constexpr int QPT = 4;            // queries per thread
constexpr int QBLK = BQ * QPT;    // 1024 queries per block
constexpr int NSPLIT = 32;        // N slices
constexpr int SLICE = NN / NSPLIT; // 256 refs per block (4 KB LDS as float4)

__global__ __launch_bounds__(BQ) void chamfer_min_kernel(
    const float* __restrict__ input,   // [B, N, 3]
    const float* __restrict__ point,   // [B, M, 3]
    float* __restrict__ out)           // [B, M], pre-init to 0xFFFFFFFF
{
    __shared__ float4 ref[SLICE];

    const int b   = blockIdx.z;
    const int n0  = blockIdx.y * SLICE;
    const int m0  = blockIdx.x * QBLK;
    const int tid = threadIdx.x;

    // --- stage reference slice into LDS with precomputed 0.5*|q|^2 ---
    const float* inb = input + (size_t)b * NN * 3;
    for (int j = tid; j < SLICE; j += BQ) {
        const int n = n0 + j;
        const float x = inb[n * 3 + 0];
        const float y = inb[n * 3 + 1];
        const float z = inb[n * 3 + 2];
        ref[j] = make_float4(x, y, z, 0.5f * (x * x + y * y + z * z));
    }

    // --- load this thread's queries into registers (negated for FMA) ---
    const float* ptb = point + (size_t)b * MM * 3;
    float nx[QPT], ny[QPT], nz[QPT], p2[QPT], tmin[QPT];
#pragma unroll
    for (int q = 0; q < QPT; ++q) {
        const int m = m0 + q * BQ + tid;
        const float x = ptb[m * 3 + 0];
        const float y = ptb[m * 3 + 1];
        const float z = ptb[m * 3 + 2];
        nx[q] = -x; ny[q] = -y; nz[q] = -z;
        p2[q] = x * x + y * y + z * z;
        tmin[q] = 3.0e38f;
    }

    __syncthreads();

    // --- inner loop: broadcast LDS read, 3 FMA + 1 min per (query, ref) ---
#pragma unroll 4
    for (int j = 0; j < SLICE; ++j) {
        const float4 r = ref[j];
#pragma unroll
        for (int q = 0; q < QPT; ++q) {
            float s = fmaf(nx[q], r.x, r.w);
            s = fmaf(ny[q], r.y, s);
            s = fmaf(nz[q], r.z, s);
            tmin[q] = fminf(tmin[q], s);
        }
    }

    // --- merge partial minima across N-slices ---
#pragma unroll
    for (int q = 0; q < QPT; ++q) {
        const int m = m0 + q * BQ + tid;
        const float d2 = fmaxf(fmaf(2.0f, tmin[q], p2[q]), 0.0f);
        atomicMin((unsigned int*)out + (size_t)b * MM + m, __float_as_uint(d2));
    }
}

extern "C" void kernel_launch(void* const* d_in, const int* in_sizes, int n_in,
                              void* d_out, int out_size, void* d_ws, size_t ws_size,
                              hipStream_t stream) {
    const float* input = (const float*)d_in[0];  // [B, N, 3]
    const float* point = (const float*)d_in[1];  // [B, M, 3]
    float* out = (float*)d_out;                  // [B, M]

    // Init out to 0xFFFFFFFF (max uint) so atomicMin(uint) works; every
    // element receives NSPLIT finite updates, so no poison survives.
    hipMemsetAsync(d_out, 0xFF, (size_t)out_size * sizeof(float), stream);

    dim3 grid(MM / QBLK, NSPLIT, BB);
    dim3 block(BQ);
    chamfer_min_kernel<<<grid, block, 0, stream>>>(input, point, out);
}

// Round 2
// 21.935 us; speedup vs baseline: 1.0340x; 1.0340x over previous
//
#include <hip/hip_runtime.h>

// One-sided Chamfer: out[b][m] = min_n || point[b][m] - input[b][n] ||^2
// B=2, N=8192, M=8192, D=3, fp32.
//
// Stage 1 (compute-bound brute force, no atomics):
//   t = 0.5*|q|^2 - p.q   (3 FMA per pair; ref float4.w holds 0.5*|q|^2)
//   partial d2 = max(2*t_min + |p|^2, 0) per N-slice -> plain store to d_ws
// Stage 2: min-reduce the NSPLIT partials per output (float4 vectorized).

constexpr int BB = 2;
constexpr int NN = 8192;
constexpr int MM = 8192;

constexpr int BQ = 256;            // threads per block (stage 1)
constexpr int QPT = 4;             // queries per thread
constexpr int QBLK = BQ * QPT;     // 1024 queries per block
constexpr int NSPLIT = 64;         // N slices -> 1024 blocks (4/CU)
constexpr int SLICE = NN / NSPLIT; // 128 refs per block (2 KB LDS as float4)
constexpr int BM = BB * MM;        // 16384 outputs

__global__ __launch_bounds__(BQ) void chamfer_partial_kernel(
    const float* __restrict__ input,   // [B, N, 3]
    const float* __restrict__ point,   // [B, M, 3]
    float* __restrict__ ws)            // [NSPLIT, B, M] partial minima
{
    __shared__ float4 ref[SLICE];

    const int b   = blockIdx.z;
    const int y   = blockIdx.y;
    const int n0  = y * SLICE;
    const int m0  = blockIdx.x * QBLK;
    const int tid = threadIdx.x;

    // --- stage reference slice into LDS with precomputed 0.5*|q|^2 ---
    const float* inb = input + (size_t)b * NN * 3;
    if (tid < SLICE) {
        const int n = n0 + tid;
        const float x = inb[n * 3 + 0];
        const float yy = inb[n * 3 + 1];
        const float z = inb[n * 3 + 2];
        ref[tid] = make_float4(x, yy, z, 0.5f * (x * x + yy * yy + z * z));
    }

    // --- load this thread's queries into registers (negated for FMA) ---
    const float* ptb = point + (size_t)b * MM * 3;
    float nx[QPT], ny[QPT], nz[QPT], p2[QPT], tmin[QPT];
#pragma unroll
    for (int q = 0; q < QPT; ++q) {
        const int m = m0 + q * BQ + tid;
        const float x = ptb[m * 3 + 0];
        const float yy = ptb[m * 3 + 1];
        const float z = ptb[m * 3 + 2];
        nx[q] = -x; ny[q] = -yy; nz[q] = -z;
        p2[q] = x * x + yy * yy + z * z;
        tmin[q] = 3.0e38f;
    }

    __syncthreads();

    // --- inner loop: 2 refs/iter, min3 fusion; 3.75 wave-instrs per pair ---
#pragma unroll 4
    for (int j = 0; j < SLICE; j += 2) {
        const float4 r0 = ref[j];
        const float4 r1 = ref[j + 1];
#pragma unroll
        for (int q = 0; q < QPT; ++q) {
            float s0 = fmaf(nx[q], r0.x, r0.w);
            s0 = fmaf(ny[q], r0.y, s0);
            s0 = fmaf(nz[q], r0.z, s0);
            float s1 = fmaf(nx[q], r1.x, r1.w);
            s1 = fmaf(ny[q], r1.y, s1);
            s1 = fmaf(nz[q], r1.z, s1);
            tmin[q] = fminf(fminf(tmin[q], s0), s1);  // -> v_min3_f32
        }
    }

    // --- plain store of this slice's partial d2 (no init, no atomics) ---
    float* wsy = ws + (size_t)y * BM + (size_t)b * MM;
#pragma unroll
    for (int q = 0; q < QPT; ++q) {
        const int m = m0 + q * BQ + tid;
        wsy[m] = fmaxf(fmaf(2.0f, tmin[q], p2[q]), 0.0f);
    }
}

// out[o] = min over y of ws[y][o], float4-vectorized: 4 MB read, L2/L3 hot.
constexpr int RB = 256;                       // threads per reduce block
constexpr int RVEC = BM / 4;                  // 4096 float4 outputs

__global__ __launch_bounds__(RB) void chamfer_reduce_kernel(
    const float* __restrict__ ws,             // [NSPLIT, BM]
    float* __restrict__ out)                  // [BM]
{
    const int o4 = blockIdx.x * RB + threadIdx.x;
    if (o4 >= RVEC) return;
    const float4* w4 = (const float4*)ws;
    float4 acc = w4[o4];
#pragma unroll 8
    for (int y = 1; y < NSPLIT; ++y) {
        const float4 v = w4[(size_t)y * RVEC + o4];
        acc.x = fminf(acc.x, v.x);
        acc.y = fminf(acc.y, v.y);
        acc.z = fminf(acc.z, v.z);
        acc.w = fminf(acc.w, v.w);
    }
    ((float4*)out)[o4] = acc;
}

extern "C" void kernel_launch(void* const* d_in, const int* in_sizes, int n_in,
                              void* d_out, int out_size, void* d_ws, size_t ws_size,
                              hipStream_t stream) {
    const float* input = (const float*)d_in[0];  // [B, N, 3]
    const float* point = (const float*)d_in[1];  // [B, M, 3]
    float* out = (float*)d_out;                  // [B, M]
    float* ws  = (float*)d_ws;                   // [NSPLIT, B, M] = 4 MB

    dim3 grid1(MM / QBLK, NSPLIT, BB);
    chamfer_partial_kernel<<<grid1, dim3(BQ), 0, stream>>>(input, point, ws);

    dim3 grid2((RVEC + RB - 1) / RB);
    chamfer_reduce_kernel<<<grid2, dim3(RB), 0, stream>>>(ws, out);
}